// Round 7
// baseline (484.605 us; speedup 1.0000x reference)
//
#include <hip/hip_runtime.h>
#include <stdint.h>

#define NPTS (96*96*96)          // 884736
#define NHALF (NPTS/2)           // 442368
#define NP5  (NPTS*5)            // 4423680 entries (point,vertex)
#define EMPTY_KEY 0xFFFFFFFFFFFFFFFFull

// Dense lattice grid (interval arithmetic from fixed domain: z,y,x in [0,95],
// image in [0,1); incl. rank-adjust, r-offset, blur padding, +/-2 margin):
//   q0 in [-3,25], q1 in [-14,14], q2 in [-16,8], q3 in [-17,3]
#define GD1 33
#define GD2 29
#define GD3 25
#define GO0 5
#define GO1 16
#define GO2 18
#define GO3 19
#define GS3 5
#define GS2 (GD3*GS3)      // 125
#define GS1 (GD2*GS2)      // 3625
#define GS0 (GD1*GS1)      // 119625
#define GCELLS (31*GS0)    // 3708375
#define GCELLS1 (GCELLS+1) // + trash cell for (never-expected) OOB
#define GSSUM (GS0+GS1+GS2+GS3)  // 123380

struct BN { float w; int next; };   // bary weight + chain link, 8B
struct LatPt { int cell[5]; float w[5]; };

__device__ __forceinline__ uint64_t mix64(uint64_t x){
  x ^= x >> 33; x *= 0xff51afd7ed558ccdULL;
  x ^= x >> 33; x *= 0xc4ceb9fe1a85ec53ULL;
  x ^= x >> 33; return x;
}

__device__ __forceinline__ int hfind(const unsigned long long* __restrict__ hkeys,
                                     const int* __restrict__ hidx,
                                     unsigned long long key, unsigned int tmask){
  unsigned int slot = (unsigned int)mix64(key) & tmask;
  while (true){
    unsigned long long k = hkeys[slot];
    if (k == key) return hidx[slot];
    if (k == EMPTY_KEY) return -1;
    slot = (slot + 1) & tmask;
  }
}

// Pack input_ channels into float4 per point
__global__ void k_qpack(const float* __restrict__ input_, float4* __restrict__ qp)
{
  int n = blockIdx.x * blockDim.x + threadIdx.x;
  if (n >= NPTS) return;
  qp[n] = make_float4(input_[n], input_[NPTS + n], input_[2 * NPTS + n], input_[3 * NPTS + n]);
}

// Shared per-point lattice math macro producing rank[5], rem0i[4], b[]
#define LATTICE_MATH(n)                                                        \
  int x = n % 96, y = (n / 96) % 96, z = n / (96 * 96);                        \
  float cf[4];                                                                 \
  cf[0] = ((float)z / 5.0f) * 2.8867513459481287f;                             \
  cf[1] = ((float)y / 5.0f) * 1.6666666666666667f;                             \
  cf[2] = ((float)x / 5.0f) * 1.1785113019775793f;                             \
  cf[3] = (imgv / 0.25f) * 0.9128709291752769f;                                \
  float elev[5];                                                               \
  float sm = 0.f;                                                              \
  _Pragma("unroll")                                                            \
  for (int i = 4; i >= 1; --i){ float c = cf[i-1]; elev[i] = sm - (float)i * c; sm += c; } \
  elev[0] = sm;                                                                \
  float rem0[5]; float sumrd_f = 0.f;                                          \
  _Pragma("unroll")                                                            \
  for (int i = 0; i < 5; i++){ float rd = rintf(elev[i] / 5.0f); rem0[i] = rd * 5.0f; sumrd_f += rd; } \
  int sum_rd = (int)sumrd_f;                                                   \
  float diff[5];                                                               \
  _Pragma("unroll")                                                            \
  for (int i = 0; i < 5; i++) diff[i] = elev[i] - rem0[i];                     \
  int rank[5];                                                                 \
  _Pragma("unroll")                                                            \
  for (int i = 0; i < 5; i++){                                                 \
    int r = 0;                                                                 \
    _Pragma("unroll")                                                          \
    for (int j = 0; j < 5; j++){                                               \
      r += (diff[j] > diff[i] || (diff[j] == diff[i] && j < i)) ? 1 : 0;       \
    }                                                                          \
    rank[i] = r + sum_rd;                                                      \
  }                                                                            \
  _Pragma("unroll")                                                            \
  for (int i = 0; i < 5; i++){                                                 \
    if (rank[i] < 0)      { rank[i] += 5; rem0[i] += 5.0f; }                   \
    else if (rank[i] > 4) { rank[i] -= 5; rem0[i] -= 5.0f; }                   \
  }                                                                            \
  float b[6] = {0.f,0.f,0.f,0.f,0.f,0.f};                                      \
  _Pragma("unroll")                                                            \
  for (int i = 0; i < 5; i++){                                                 \
    float v = (elev[i] - rem0[i]) / 5.0f;                                      \
    b[4 - rank[i]] += v;                                                       \
    b[5 - rank[i]] -= v;                                                       \
  }                                                                            \
  b[0] += 1.0f + b[5];                                                         \
  int rem0i[4];                                                                \
  _Pragma("unroll")                                                            \
  for (int i = 0; i < 4; i++) rem0i[i] = (int)rem0[i];

// Dense-path per-point result: 5 cells + 5 weights (shared by build & slice —
// single implementation keeps the fp32 arithmetic bit-identical).
__device__ __forceinline__ LatPt lat_compute(int n, float imgv)
{
  LATTICE_MATH(n)
  LatPt p;
  #pragma unroll
  for (int r = 0; r < 5; r++){
    int q0 = (rem0i[0] / 5) - (rank[0] < 5 - r ? 0 : 1) + GO0;
    int q1 = (rem0i[1] / 5) - (rank[1] < 5 - r ? 0 : 1) + GO1;
    int q2 = (rem0i[2] / 5) - (rank[2] < 5 - r ? 0 : 1) + GO2;
    int q3 = (rem0i[3] / 5) - (rank[3] < 5 - r ? 0 : 1) + GO3;
    int cell = (((q0 * GD1 + q1) * GD2 + q2) * GD3 + q3) * 5 + r;
    if ((unsigned)cell >= (unsigned)GCELLS) cell = GCELLS;
    p.cell[r] = cell;
    p.w[r] = b[r];
  }
  return p;
}

// ============================ DENSE-GRID PATH ============================

// Phase 1: two points per thread — compute both lattice results first, then
// issue all 10 independent atomicExch back-to-back (maximize outstanding
// atomics; build is coherence-latency-bound), then the dependent stores.
__global__ void k_build_d2(const float* __restrict__ image,
                           int* __restrict__ head,
                           BN* __restrict__ bnext)
{
  int t = blockIdx.x * blockDim.x + threadIdx.x;
  if (t >= NHALF) return;
  int nA = t, nB = t + NHALF;

  float imgA = image[nA], imgB = image[nB];
  LatPt A = lat_compute(nA, imgA);
  LatPt B = lat_compute(nB, imgB);

  int oldA[5], oldB[5];
  #pragma unroll
  for (int r = 0; r < 5; r++) oldA[r] = atomicExch(&head[A.cell[r]], nA * 5 + r);
  #pragma unroll
  for (int r = 0; r < 5; r++) oldB[r] = atomicExch(&head[B.cell[r]], nB * 5 + r);

  #pragma unroll
  for (int r = 0; r < 5; r++){ BN bn; bn.w = A.w[r]; bn.next = oldA[r]; bnext[nA * 5 + r] = bn; }
  #pragma unroll
  for (int r = 0; r < 5; r++){ BN bn; bn.w = B.w[r]; bn.next = oldB[r]; bnext[nB * 5 + r] = bn; }
}

// Phase 2: gather-splat per cell; zeros for empty cells; emits occupancy
// bitmap via wave ballot.
__global__ void k_gather_d(const int* __restrict__ head,
                           const BN* __restrict__ bnext,
                           const float4* __restrict__ qp,
                           float* __restrict__ vals,
                           unsigned int* __restrict__ bitmap)
{
  int c = blockIdx.x * blockDim.x + threadIdx.x;
  int e = -1;
  if (c < GCELLS1) e = head[c];
  bool occ = (e >= 0);
  unsigned long long mask = __ballot(occ);
  int lane = threadIdx.x & 63;
  if (lane == 0)       bitmap[c >> 5] = (unsigned int)(mask & 0xffffffffu);
  else if (lane == 32) bitmap[c >> 5] = (unsigned int)(mask >> 32);
  if (c >= GCELLS1) return;

  float s0 = 0.f, s1 = 0.f, s2 = 0.f, s3 = 0.f, s4 = 0.f;
  while (e >= 0){
    BN bn = bnext[e];
    float4 q = qp[e / 5];
    s0 += bn.w * q.x; s1 += bn.w * q.y; s2 += bn.w * q.z; s3 += bn.w * q.w; s4 += bn.w;
    e = bn.next;
  }
  float* v = vals + (size_t)c * 5;
  v[0] = s0; v[1] = s1; v[2] = s2; v[3] = s3; v[4] = s4;
}

// Phase 3: dense blur pass — neighbors are constant flat-index deltas.
// zfill=1 only on pass 1 (ping-pong invariant zeroes the rest).
__global__ void k_blur_d(const unsigned int* __restrict__ bitmap,
                         const float* __restrict__ vin,
                         float* __restrict__ vout,
                         int dPa, int dPb, int dMa, int dMb, int zfill)
{
  int c = blockIdx.x * blockDim.x + threadIdx.x;
  if (c >= GCELLS) return;
  unsigned int w = bitmap[c >> 5];
  if (!((w >> (c & 31)) & 1u)){
    if (zfill){
      float* vo = vout + (size_t)c * 5;
      vo[0] = 0.f; vo[1] = 0.f; vo[2] = 0.f; vo[3] = 0.f; vo[4] = 0.f;
    }
    return;
  }
  int r = c % 5;
  int p1 = c + (r == 4 ? dPb : dPa);
  int p2 = c + (r == 0 ? dMb : dMa);
  float* vo = vout + (size_t)c * 5;
  const float* va = vin + (size_t)c * 5;
  const float* n1 = vin + (size_t)p1 * 5;  // empty neighbors hold zeros
  const float* n2 = vin + (size_t)p2 * 5;
  #pragma unroll
  for (int ch = 0; ch < 5; ch++)
    vo[ch] = 0.5f * va[ch] + 0.25f * (n1[ch] + n2[ch]);
}

// Phase 4: slice + normalize — recomputes cells & weights (bit-identical to
// build via lat_compute).
__global__ void k_slice_d(const float* __restrict__ image,
                          const float* __restrict__ vals,
                          float* __restrict__ out)
{
  int n = blockIdx.x * blockDim.x + threadIdx.x;
  if (n >= NPTS) return;
  LatPt P = lat_compute(n, image[n]);

  float s0 = 0.f, s1 = 0.f, s2 = 0.f, s3 = 0.f, s4 = 0.f;
  #pragma unroll
  for (int r = 0; r < 5; r++){
    float w = P.w[r];
    const float* v = vals + (size_t)P.cell[r] * 5;
    s0 += w * v[0]; s1 += w * v[1]; s2 += w * v[2]; s3 += w * v[3]; s4 += w * v[4];
  }
  float denom = s4 + 2.2204460492503131e-16f;
  out[n]            = s0 / denom;
  out[NPTS + n]     = s1 / denom;
  out[2 * NPTS + n] = s2 / denom;
  out[3 * NPTS + n] = s3 / denom;
}

// ============================ HASH FALLBACK PATH ============================

__global__ void k_build_h(const float* __restrict__ image,
                          unsigned long long* __restrict__ hkeys,
                          unsigned int tmask,
                          int* __restrict__ slots,
                          float* __restrict__ baryo,
                          int* __restrict__ head,
                          int* __restrict__ nexte,
                          int* __restrict__ hidx,
                          unsigned long long* __restrict__ lkeys,
                          int* __restrict__ lslot,
                          int* __restrict__ cnt,
                          int Mmax)
{
  int n = blockIdx.x * blockDim.x + threadIdx.x;
  if (n >= NPTS) return;
  float imgv = image[n];
  LATTICE_MATH(n)

  #pragma unroll
  for (int r = 0; r < 5; r++){
    long long enc = 0;
    #pragma unroll
    for (int i = 0; i < 4; i++){
      int ki = rem0i[i] + (rank[i] < 5 - r ? r : r - 5);
      enc = enc * 8192 + (long long)(ki + 4096);
    }
    unsigned long long key = (unsigned long long)enc;
    unsigned int slot = (unsigned int)mix64(key) & tmask;
    bool won = false;
    while (true){
      unsigned long long k = hkeys[slot];
      if (k == key) break;
      if (k == EMPTY_KEY){
        unsigned long long prev = atomicCAS(&hkeys[slot], EMPTY_KEY, key);
        if (prev == EMPTY_KEY){ won = true; break; }
        if (prev == key) break;
      }
      slot = (slot + 1) & tmask;
    }
    if (won){
      int m = atomicAdd(cnt, 1);
      if (m < Mmax){ hidx[slot] = m; lkeys[m] = key; lslot[m] = (int)slot; }
    }
    int e = n * 5 + r;
    slots[e] = (int)slot;
    baryo[e] = b[r];
    int old = atomicExch(&head[slot], e);
    nexte[e] = old;
  }
}

__global__ void k_gather_h(const int* __restrict__ lslot,
                           const int* __restrict__ head,
                           const int* __restrict__ nexte,
                           const float* __restrict__ bary,
                           const float4* __restrict__ qp,
                           float* __restrict__ vals,
                           const int* __restrict__ counterM, int Mmax)
{
  int m = blockIdx.x * blockDim.x + threadIdx.x;
  int M = *counterM; if (M > Mmax) M = Mmax;
  if (m >= M) return;
  int e = head[lslot[m]];
  float s0 = 0.f, s1 = 0.f, s2 = 0.f, s3 = 0.f, s4 = 0.f;
  while (e >= 0){
    float w = bary[e];
    float4 q = qp[e / 5];
    s0 += w * q.x; s1 += w * q.y; s2 += w * q.z; s3 += w * q.w; s4 += w;
    e = nexte[e];
  }
  float* v = vals + (size_t)m * 5;
  v[0] = s0; v[1] = s1; v[2] = s2; v[3] = s3; v[4] = s4;
}

__global__ void k_blur_h(const unsigned long long* __restrict__ hkeys,
                         const int* __restrict__ hidx,
                         const unsigned long long* __restrict__ lkeys,
                         const float* __restrict__ vin,
                         float* __restrict__ vout,
                         const int* __restrict__ counterM,
                         unsigned int tmask, long long delta, int Mmax)
{
  int m = blockIdx.x * blockDim.x + threadIdx.x;
  int M = *counterM; if (M > Mmax) M = Mmax;
  if (m >= M) return;
  unsigned long long key = lkeys[m];
  int p1 = hfind(hkeys, hidx, (unsigned long long)((long long)key + delta), tmask);
  int p2 = hfind(hkeys, hidx, (unsigned long long)((long long)key - delta), tmask);
  #pragma unroll
  for (int c = 0; c < 5; c++){
    float n1 = (p1 >= 0) ? vin[p1 * 5 + c] : 0.0f;
    float n2 = (p2 >= 0) ? vin[p2 * 5 + c] : 0.0f;
    vout[m * 5 + c] = 0.5f * vin[m * 5 + c] + 0.25f * (n1 + n2);
  }
}

__global__ void k_slice_h(const int* __restrict__ slots,
                          const float* __restrict__ bary,
                          const int* __restrict__ hidx,
                          const float* __restrict__ vals,
                          float* __restrict__ out,
                          const int* __restrict__ counterM, int Mmax)
{
  int n = blockIdx.x * blockDim.x + threadIdx.x;
  if (n >= NPTS) return;
  int Mact = *counterM; if (Mact > Mmax) Mact = Mmax;
  float s[5] = {0.f,0.f,0.f,0.f,0.f};
  #pragma unroll
  for (int r = 0; r < 5; r++){
    int m = hidx[slots[n * 5 + r]];
    float w = bary[n * 5 + r];
    if (m >= 0 && m < Mact){
      #pragma unroll
      for (int c = 0; c < 5; c++) s[c] += w * vals[m * 5 + c];
    }
  }
  float denom = s[4] + 2.2204460492503131e-16f;
  #pragma unroll
  for (int c = 0; c < 4; c++) out[c * NPTS + n] = s[c] / denom;
}

// ============================ HOST ============================

extern "C" void kernel_launch(void* const* d_in, const int* in_sizes, int n_in,
                              void* d_out, int out_size, void* d_ws, size_t ws_size,
                              hipStream_t stream)
{
  const float* input_ = (const float*)d_in[0];
  const float* image  = (const float*)d_in[1];
  float* out = (float*)d_out;
  char* ws = (char*)d_ws;

  const int NB = (NPTS + 255) / 256;
  const int HB = (NHALF + 255) / 256;
  const int CB = (GCELLS1 + 255) / 256;
  const size_t BMWORDS = (size_t)CB * 8;   // 32 cells/word, covers CB*256 cells

  // ---- Dense-grid path workspace ----
  size_t o = 0;
  size_t off_head  = o; o += (size_t)GCELLS1 * 4;      o = (o + 255) & ~(size_t)255;
  size_t off_bm    = o; o += BMWORDS * 4;              o = (o + 255) & ~(size_t)255;
  size_t off_bnext = o; o += (size_t)NP5 * 8;          o = (o + 255) & ~(size_t)255;
  size_t off_qp    = o; o += (size_t)NPTS * 16;        o = (o + 255) & ~(size_t)255;
  size_t off_vA    = o; o += (size_t)GCELLS1 * 5 * 4;  o = (o + 255) & ~(size_t)255;
  size_t off_vB    = o; o += (size_t)GCELLS1 * 5 * 4;
  const size_t dense_need = o;

  if (dense_need <= ws_size){
    int*          head   = (int*)(ws + off_head);
    unsigned int* bitmap = (unsigned int*)(ws + off_bm);
    BN*           bnext  = (BN*)(ws + off_bnext);
    float4*       qp     = (float4*)(ws + off_qp);
    float*        valsA  = (float*)(ws + off_vA);
    float*        valsB  = (float*)(ws + off_vB);

    hipMemsetAsync(head, 0xFF, (size_t)GCELLS1 * 4, stream);

    k_qpack<<<NB, 256, 0, stream>>>(input_, qp);
    k_build_d2<<<HB, 256, 0, stream>>>(image, head, bnext);
    k_gather_d<<<CB, 256, 0, stream>>>(head, bnext, qp, valsA, bitmap);

    const int Sj[5] = { GS0, GS1, GS2, GS3, 0 };
    float* vin = valsA; float* vout = valsB;
    for (int j = 0; j < 5; j++){
      int dPa = 1 - Sj[j];
      int dPb = GSSUM - Sj[j] - 4;
      int dMa = Sj[j] - 1;
      int dMb = Sj[j] - GSSUM + 4;
      k_blur_d<<<CB, 256, 0, stream>>>(bitmap, vin, vout, dPa, dPb, dMa, dMb,
                                       (j == 0) ? 1 : 0);
      float* t = vin; vin = vout; vout = t;
    }

    k_slice_d<<<NB, 256, 0, stream>>>(image, vin, out);
    return;
  }

  // ---- Hash fallback path ----
  struct Cfg { int tb; size_t M; };
  const Cfg cfgs[] = {
    {23, (size_t)NP5}, {23, 3200000}, {22, 2000000}, {21, 1500000}, {20, 1000000}
  };
  const int NCFG = sizeof(cfgs) / sizeof(cfgs[0]);

  int tbits = 20; size_t Mmax = 1000000;
  size_t off_hkeys = 0, off_hidx = 0, off_head2 = 0, off_cnt = 0, off_slots2 = 0,
         off_bary = 0, off_next = 0, off_lkeys = 0, off_lslot = 0, off_qp2 = 0,
         off_vA2 = 0, off_vB2 = 0;
  for (int i = 0; i < NCFG; i++){
    size_t T = (size_t)1 << cfgs[i].tb; size_t M = cfgs[i].M;
    size_t oo = 0;
    off_hkeys = oo; oo += T * 8;
    off_hidx  = oo; oo += T * 4;
    off_head2 = oo; oo += T * 4;
    off_cnt   = oo; oo += 256;
    off_slots2= oo; oo += (size_t)NP5 * 4;
    off_bary  = oo; oo += (size_t)NP5 * 4;
    off_next  = oo; oo += (size_t)NP5 * 4;
    off_lkeys = oo; oo += M * 8;
    off_lslot = oo; oo += M * 4;
    off_qp2   = oo; oo += (size_t)NPTS * 16;
    off_vA2   = oo; oo += M * 5 * 4;
    off_vB2   = oo; oo += M * 5 * 4;
    tbits = cfgs[i].tb; Mmax = M;
    if (oo <= ws_size) break;
  }
  size_t T = (size_t)1 << tbits;
  unsigned int tmask = (unsigned int)(T - 1);

  unsigned long long* hkeys = (unsigned long long*)(ws + off_hkeys);
  int*                hidx  = (int*)(ws + off_hidx);
  int*                head  = (int*)(ws + off_head2);
  int*                cnt   = (int*)(ws + off_cnt);
  int*                slots = (int*)(ws + off_slots2);
  float*              bary  = (float*)(ws + off_bary);
  int*                nexte = (int*)(ws + off_next);
  unsigned long long* lkeys = (unsigned long long*)(ws + off_lkeys);
  int*                lslot = (int*)(ws + off_lslot);
  float4*             qp    = (float4*)(ws + off_qp2);
  float*              valsA = (float*)(ws + off_vA2);
  float*              valsB = (float*)(ws + off_vB2);

  hipMemsetAsync(ws + off_hkeys, 0xFF, T * 8 + T * 4 + T * 4, stream);
  hipMemsetAsync(ws + off_cnt, 0, 256, stream);

  const int MB = (int)((Mmax + 255) / 256);

  k_qpack<<<NB, 256, 0, stream>>>(input_, qp);
  k_build_h<<<NB, 256, 0, stream>>>(image, hkeys, tmask, slots, bary, head, nexte,
                                    hidx, lkeys, lslot, cnt, (int)Mmax);
  k_gather_h<<<MB, 256, 0, stream>>>(lslot, head, nexte, bary, qp, valsA, cnt, (int)Mmax);

  const long long P3 = 1ll << 39, P2 = 1ll << 26, P1 = 1ll << 13, P0 = 1ll;
  const long long Dall = P3 + P2 + P1 + P0;
  const long long deltas[5] = { Dall - 5*P3, Dall - 5*P2, Dall - 5*P1, Dall - 5*P0, Dall };

  float* vin = valsA; float* vout = valsB;
  for (int j = 0; j < 5; j++){
    k_blur_h<<<MB, 256, 0, stream>>>(hkeys, hidx, lkeys, vin, vout, cnt, tmask, deltas[j], (int)Mmax);
    float* t = vin; vin = vout; vout = t;
  }

  k_slice_h<<<NB, 256, 0, stream>>>(slots, bary, hidx, vin, out, cnt, (int)Mmax);
}

// Round 8
// 282.448 us; speedup vs baseline: 1.7157x; 1.7157x over previous
//
#include <hip/hip_runtime.h>
#include <stdint.h>

#define NPTS (96*96*96)          // 884736
#define NP5  (NPTS*5)            // 4423680 entries (point,vertex)
#define EMPTY_KEY 0xFFFFFFFFFFFFFFFFull

// Dense lattice grid (interval arithmetic from fixed domain: z,y,x in [0,95],
// image in [0,1); incl. rank-adjust, r-offset, blur padding, +/-2 margin):
//   q0 in [-3,25], q1 in [-14,14], q2 in [-16,8], q3 in [-17,3]
#define GD1 33
#define GD2 29
#define GD3 25
#define GO0 5
#define GO1 16
#define GO2 18
#define GO3 19
#define GS3 5
#define GS2 (GD3*GS3)      // 125
#define GS1 (GD2*GS2)      // 3625
#define GS0 (GD1*GS1)      // 119625
#define GCELLS (31*GS0)    // 3708375
#define GCELLS1 (GCELLS+1) // + trash cell for (never-expected) OOB
#define GSSUM (GS0+GS1+GS2+GS3)  // 123380

#define LHS 2048           // block-local LDS hash slots (1280 entries max -> load 0.625)

struct BN { float w; int next; };   // bary weight + chain link, 8B
struct LatPt { int cell[5]; float w[5]; };

__device__ __forceinline__ uint64_t mix64(uint64_t x){
  x ^= x >> 33; x *= 0xff51afd7ed558ccdULL;
  x ^= x >> 33; x *= 0xc4ceb9fe1a85ec53ULL;
  x ^= x >> 33; return x;
}

__device__ __forceinline__ int hfind(const unsigned long long* __restrict__ hkeys,
                                     const int* __restrict__ hidx,
                                     unsigned long long key, unsigned int tmask){
  unsigned int slot = (unsigned int)mix64(key) & tmask;
  while (true){
    unsigned long long k = hkeys[slot];
    if (k == key) return hidx[slot];
    if (k == EMPTY_KEY) return -1;
    slot = (slot + 1) & tmask;
  }
}

// Pack input_ channels into float4 per point
__global__ void k_qpack(const float* __restrict__ input_, float4* __restrict__ qp)
{
  int n = blockIdx.x * blockDim.x + threadIdx.x;
  if (n >= NPTS) return;
  qp[n] = make_float4(input_[n], input_[NPTS + n], input_[2 * NPTS + n], input_[3 * NPTS + n]);
}

// Shared per-point lattice math macro producing rank[5], rem0i[4], b[]
#define LATTICE_MATH(n)                                                        \
  int x = n % 96, y = (n / 96) % 96, z = n / (96 * 96);                        \
  float cf[4];                                                                 \
  cf[0] = ((float)z / 5.0f) * 2.8867513459481287f;                             \
  cf[1] = ((float)y / 5.0f) * 1.6666666666666667f;                             \
  cf[2] = ((float)x / 5.0f) * 1.1785113019775793f;                             \
  cf[3] = (imgv / 0.25f) * 0.9128709291752769f;                                \
  float elev[5];                                                               \
  float sm = 0.f;                                                              \
  _Pragma("unroll")                                                            \
  for (int i = 4; i >= 1; --i){ float c = cf[i-1]; elev[i] = sm - (float)i * c; sm += c; } \
  elev[0] = sm;                                                                \
  float rem0[5]; float sumrd_f = 0.f;                                          \
  _Pragma("unroll")                                                            \
  for (int i = 0; i < 5; i++){ float rd = rintf(elev[i] / 5.0f); rem0[i] = rd * 5.0f; sumrd_f += rd; } \
  int sum_rd = (int)sumrd_f;                                                   \
  float diff[5];                                                               \
  _Pragma("unroll")                                                            \
  for (int i = 0; i < 5; i++) diff[i] = elev[i] - rem0[i];                     \
  int rank[5];                                                                 \
  _Pragma("unroll")                                                            \
  for (int i = 0; i < 5; i++){                                                 \
    int r = 0;                                                                 \
    _Pragma("unroll")                                                          \
    for (int j = 0; j < 5; j++){                                               \
      r += (diff[j] > diff[i] || (diff[j] == diff[i] && j < i)) ? 1 : 0;       \
    }                                                                          \
    rank[i] = r + sum_rd;                                                      \
  }                                                                            \
  _Pragma("unroll")                                                            \
  for (int i = 0; i < 5; i++){                                                 \
    if (rank[i] < 0)      { rank[i] += 5; rem0[i] += 5.0f; }                   \
    else if (rank[i] > 4) { rank[i] -= 5; rem0[i] -= 5.0f; }                   \
  }                                                                            \
  float b[6] = {0.f,0.f,0.f,0.f,0.f,0.f};                                      \
  _Pragma("unroll")                                                            \
  for (int i = 0; i < 5; i++){                                                 \
    float v = (elev[i] - rem0[i]) / 5.0f;                                      \
    b[4 - rank[i]] += v;                                                       \
    b[5 - rank[i]] -= v;                                                       \
  }                                                                            \
  b[0] += 1.0f + b[5];                                                         \
  int rem0i[4];                                                                \
  _Pragma("unroll")                                                            \
  for (int i = 0; i < 4; i++) rem0i[i] = (int)rem0[i];

// Dense-path per-point result: 5 cells + 5 weights (shared by build & slice —
// single implementation keeps the fp32 arithmetic bit-identical).
__device__ __forceinline__ LatPt lat_compute(int n, float imgv)
{
  LATTICE_MATH(n)
  LatPt p;
  #pragma unroll
  for (int r = 0; r < 5; r++){
    int q0 = (rem0i[0] / 5) - (rank[0] < 5 - r ? 0 : 1) + GO0;
    int q1 = (rem0i[1] / 5) - (rank[1] < 5 - r ? 0 : 1) + GO1;
    int q2 = (rem0i[2] / 5) - (rank[2] < 5 - r ? 0 : 1) + GO2;
    int q3 = (rem0i[3] / 5) - (rank[3] < 5 - r ? 0 : 1) + GO3;
    int cell = (((q0 * GD1 + q1) * GD2 + q2) * GD3 + q3) * 5 + r;
    if ((unsigned)cell >= (unsigned)GCELLS) cell = GCELLS;
    p.cell[r] = cell;
    p.w[r] = b[r];
  }
  return p;
}

// ============================ DENSE-GRID PATH ============================

// Phase 1: block-local chain aggregation. Each block dedupes its 1280
// (cell,entry) pairs through an LDS hash; per distinct cell, ONE global
// atomicExch splices the block-local chain into the global chain (tail ->
// global old head). Cuts global atomic transactions by the block dedup
// factor; LDS atomics are on-CU and cheap.
__global__ void k_build_lds(const float* __restrict__ image,
                            int* __restrict__ head,
                            BN* __restrict__ bnext)
{
  __shared__ int ls_cell[LHS];
  __shared__ int ls_head[LHS];

  int tid = threadIdx.x;
  #pragma unroll
  for (int i = 0; i < LHS / 256; i++){
    ls_cell[tid + 256 * i] = -1;
    ls_head[tid + 256 * i] = -1;
  }
  __syncthreads();

  int n = blockIdx.x * 256 + tid;
  LatPt P = lat_compute(n, image[n]);
  int blockBase = blockIdx.x * 1280;

  int lold[5]; unsigned int hs[5];
  #pragma unroll
  for (int r = 0; r < 5; r++){
    int cell = P.cell[r];
    unsigned int h = ((unsigned int)cell * 2654435761u) & (LHS - 1);
    while (true){
      int prev = atomicCAS(&ls_cell[h], -1, cell);
      if (prev == -1 || prev == cell) break;
      h = (h + 1) & (LHS - 1);
    }
    hs[r] = h;
    lold[r] = atomicExch(&ls_head[h], tid * 5 + r);   // block-local chain push
  }
  __syncthreads();

  // One global splice per distinct cell (done by the local-chain tail: the
  // entry whose LDS exch returned -1), then everyone writes their BN node.
  #pragma unroll
  for (int r = 0; r < 5; r++){
    int e = blockBase + tid * 5 + r;
    int nxt;
    if (lold[r] < 0){
      int lhead = ls_head[hs[r]];                       // final local head
      nxt = atomicExch(&head[P.cell[r]], blockBase + lhead);
    } else {
      nxt = blockBase + lold[r];
    }
    BN bn; bn.w = P.w[r]; bn.next = nxt;
    bnext[e] = bn;
  }
}

// Phase 2: gather-splat per cell; zeros for empty cells; emits occupancy
// bitmap via wave ballot.
__global__ void k_gather_d(const int* __restrict__ head,
                           const BN* __restrict__ bnext,
                           const float4* __restrict__ qp,
                           float* __restrict__ vals,
                           unsigned int* __restrict__ bitmap)
{
  int c = blockIdx.x * blockDim.x + threadIdx.x;
  int e = -1;
  if (c < GCELLS1) e = head[c];
  bool occ = (e >= 0);
  unsigned long long mask = __ballot(occ);
  int lane = threadIdx.x & 63;
  if (lane == 0)       bitmap[c >> 5] = (unsigned int)(mask & 0xffffffffu);
  else if (lane == 32) bitmap[c >> 5] = (unsigned int)(mask >> 32);
  if (c >= GCELLS1) return;

  float s0 = 0.f, s1 = 0.f, s2 = 0.f, s3 = 0.f, s4 = 0.f;
  while (e >= 0){
    BN bn = bnext[e];
    float4 q = qp[e / 5];
    s0 += bn.w * q.x; s1 += bn.w * q.y; s2 += bn.w * q.z; s3 += bn.w * q.w; s4 += bn.w;
    e = bn.next;
  }
  float* v = vals + (size_t)c * 5;
  v[0] = s0; v[1] = s1; v[2] = s2; v[3] = s3; v[4] = s4;
}

// Phase 3: dense blur pass — neighbors are constant flat-index deltas.
// zfill=1 only on pass 1 (ping-pong invariant zeroes the rest).
__global__ void k_blur_d(const unsigned int* __restrict__ bitmap,
                         const float* __restrict__ vin,
                         float* __restrict__ vout,
                         int dPa, int dPb, int dMa, int dMb, int zfill)
{
  int c = blockIdx.x * blockDim.x + threadIdx.x;
  if (c >= GCELLS) return;
  unsigned int w = bitmap[c >> 5];
  if (!((w >> (c & 31)) & 1u)){
    if (zfill){
      float* vo = vout + (size_t)c * 5;
      vo[0] = 0.f; vo[1] = 0.f; vo[2] = 0.f; vo[3] = 0.f; vo[4] = 0.f;
    }
    return;
  }
  int r = c % 5;
  int p1 = c + (r == 4 ? dPb : dPa);
  int p2 = c + (r == 0 ? dMb : dMa);
  float* vo = vout + (size_t)c * 5;
  const float* va = vin + (size_t)c * 5;
  const float* n1 = vin + (size_t)p1 * 5;  // empty neighbors hold zeros
  const float* n2 = vin + (size_t)p2 * 5;
  #pragma unroll
  for (int ch = 0; ch < 5; ch++)
    vo[ch] = 0.5f * va[ch] + 0.25f * (n1[ch] + n2[ch]);
}

// Phase 4: slice + normalize — recomputes cells & weights (bit-identical to
// build via lat_compute).
__global__ void k_slice_d(const float* __restrict__ image,
                          const float* __restrict__ vals,
                          float* __restrict__ out)
{
  int n = blockIdx.x * blockDim.x + threadIdx.x;
  if (n >= NPTS) return;
  LatPt P = lat_compute(n, image[n]);

  float s0 = 0.f, s1 = 0.f, s2 = 0.f, s3 = 0.f, s4 = 0.f;
  #pragma unroll
  for (int r = 0; r < 5; r++){
    float w = P.w[r];
    const float* v = vals + (size_t)P.cell[r] * 5;
    s0 += w * v[0]; s1 += w * v[1]; s2 += w * v[2]; s3 += w * v[3]; s4 += w * v[4];
  }
  float denom = s4 + 2.2204460492503131e-16f;
  out[n]            = s0 / denom;
  out[NPTS + n]     = s1 / denom;
  out[2 * NPTS + n] = s2 / denom;
  out[3 * NPTS + n] = s3 / denom;
}

// ============================ HASH FALLBACK PATH ============================

__global__ void k_build_h(const float* __restrict__ image,
                          unsigned long long* __restrict__ hkeys,
                          unsigned int tmask,
                          int* __restrict__ slots,
                          float* __restrict__ baryo,
                          int* __restrict__ head,
                          int* __restrict__ nexte,
                          int* __restrict__ hidx,
                          unsigned long long* __restrict__ lkeys,
                          int* __restrict__ lslot,
                          int* __restrict__ cnt,
                          int Mmax)
{
  int n = blockIdx.x * blockDim.x + threadIdx.x;
  if (n >= NPTS) return;
  float imgv = image[n];
  LATTICE_MATH(n)

  #pragma unroll
  for (int r = 0; r < 5; r++){
    long long enc = 0;
    #pragma unroll
    for (int i = 0; i < 4; i++){
      int ki = rem0i[i] + (rank[i] < 5 - r ? r : r - 5);
      enc = enc * 8192 + (long long)(ki + 4096);
    }
    unsigned long long key = (unsigned long long)enc;
    unsigned int slot = (unsigned int)mix64(key) & tmask;
    bool won = false;
    while (true){
      unsigned long long k = hkeys[slot];
      if (k == key) break;
      if (k == EMPTY_KEY){
        unsigned long long prev = atomicCAS(&hkeys[slot], EMPTY_KEY, key);
        if (prev == EMPTY_KEY){ won = true; break; }
        if (prev == key) break;
      }
      slot = (slot + 1) & tmask;
    }
    if (won){
      int m = atomicAdd(cnt, 1);
      if (m < Mmax){ hidx[slot] = m; lkeys[m] = key; lslot[m] = (int)slot; }
    }
    int e = n * 5 + r;
    slots[e] = (int)slot;
    baryo[e] = b[r];
    int old = atomicExch(&head[slot], e);
    nexte[e] = old;
  }
}

__global__ void k_gather_h(const int* __restrict__ lslot,
                           const int* __restrict__ head,
                           const int* __restrict__ nexte,
                           const float* __restrict__ bary,
                           const float4* __restrict__ qp,
                           float* __restrict__ vals,
                           const int* __restrict__ counterM, int Mmax)
{
  int m = blockIdx.x * blockDim.x + threadIdx.x;
  int M = *counterM; if (M > Mmax) M = Mmax;
  if (m >= M) return;
  int e = head[lslot[m]];
  float s0 = 0.f, s1 = 0.f, s2 = 0.f, s3 = 0.f, s4 = 0.f;
  while (e >= 0){
    float w = bary[e];
    float4 q = qp[e / 5];
    s0 += w * q.x; s1 += w * q.y; s2 += w * q.z; s3 += w * q.w; s4 += w;
    e = nexte[e];
  }
  float* v = vals + (size_t)m * 5;
  v[0] = s0; v[1] = s1; v[2] = s2; v[3] = s3; v[4] = s4;
}

__global__ void k_blur_h(const unsigned long long* __restrict__ hkeys,
                         const int* __restrict__ hidx,
                         const unsigned long long* __restrict__ lkeys,
                         const float* __restrict__ vin,
                         float* __restrict__ vout,
                         const int* __restrict__ counterM,
                         unsigned int tmask, long long delta, int Mmax)
{
  int m = blockIdx.x * blockDim.x + threadIdx.x;
  int M = *counterM; if (M > Mmax) M = Mmax;
  if (m >= M) return;
  unsigned long long key = lkeys[m];
  int p1 = hfind(hkeys, hidx, (unsigned long long)((long long)key + delta), tmask);
  int p2 = hfind(hkeys, hidx, (unsigned long long)((long long)key - delta), tmask);
  #pragma unroll
  for (int c = 0; c < 5; c++){
    float n1 = (p1 >= 0) ? vin[p1 * 5 + c] : 0.0f;
    float n2 = (p2 >= 0) ? vin[p2 * 5 + c] : 0.0f;
    vout[m * 5 + c] = 0.5f * vin[m * 5 + c] + 0.25f * (n1 + n2);
  }
}

__global__ void k_slice_h(const int* __restrict__ slots,
                          const float* __restrict__ bary,
                          const int* __restrict__ hidx,
                          const float* __restrict__ vals,
                          float* __restrict__ out,
                          const int* __restrict__ counterM, int Mmax)
{
  int n = blockIdx.x * blockDim.x + threadIdx.x;
  if (n >= NPTS) return;
  int Mact = *counterM; if (Mact > Mmax) Mact = Mmax;
  float s[5] = {0.f,0.f,0.f,0.f,0.f};
  #pragma unroll
  for (int r = 0; r < 5; r++){
    int m = hidx[slots[n * 5 + r]];
    float w = bary[n * 5 + r];
    if (m >= 0 && m < Mact){
      #pragma unroll
      for (int c = 0; c < 5; c++) s[c] += w * vals[m * 5 + c];
    }
  }
  float denom = s[4] + 2.2204460492503131e-16f;
  #pragma unroll
  for (int c = 0; c < 4; c++) out[c * NPTS + n] = s[c] / denom;
}

// ============================ HOST ============================

extern "C" void kernel_launch(void* const* d_in, const int* in_sizes, int n_in,
                              void* d_out, int out_size, void* d_ws, size_t ws_size,
                              hipStream_t stream)
{
  const float* input_ = (const float*)d_in[0];
  const float* image  = (const float*)d_in[1];
  float* out = (float*)d_out;
  char* ws = (char*)d_ws;

  const int NB = (NPTS + 255) / 256;
  const int CB = (GCELLS1 + 255) / 256;
  const size_t BMWORDS = (size_t)CB * 8;   // 32 cells/word, covers CB*256 cells

  // ---- Dense-grid path workspace ----
  size_t o = 0;
  size_t off_head  = o; o += (size_t)GCELLS1 * 4;      o = (o + 255) & ~(size_t)255;
  size_t off_bm    = o; o += BMWORDS * 4;              o = (o + 255) & ~(size_t)255;
  size_t off_bnext = o; o += (size_t)NP5 * 8;          o = (o + 255) & ~(size_t)255;
  size_t off_qp    = o; o += (size_t)NPTS * 16;        o = (o + 255) & ~(size_t)255;
  size_t off_vA    = o; o += (size_t)GCELLS1 * 5 * 4;  o = (o + 255) & ~(size_t)255;
  size_t off_vB    = o; o += (size_t)GCELLS1 * 5 * 4;
  const size_t dense_need = o;

  if (dense_need <= ws_size){
    int*          head   = (int*)(ws + off_head);
    unsigned int* bitmap = (unsigned int*)(ws + off_bm);
    BN*           bnext  = (BN*)(ws + off_bnext);
    float4*       qp     = (float4*)(ws + off_qp);
    float*        valsA  = (float*)(ws + off_vA);
    float*        valsB  = (float*)(ws + off_vB);

    hipMemsetAsync(head, 0xFF, (size_t)GCELLS1 * 4, stream);

    k_qpack<<<NB, 256, 0, stream>>>(input_, qp);
    k_build_lds<<<NB, 256, 0, stream>>>(image, head, bnext);
    k_gather_d<<<CB, 256, 0, stream>>>(head, bnext, qp, valsA, bitmap);

    const int Sj[5] = { GS0, GS1, GS2, GS3, 0 };
    float* vin = valsA; float* vout = valsB;
    for (int j = 0; j < 5; j++){
      int dPa = 1 - Sj[j];
      int dPb = GSSUM - Sj[j] - 4;
      int dMa = Sj[j] - 1;
      int dMb = Sj[j] - GSSUM + 4;
      k_blur_d<<<CB, 256, 0, stream>>>(bitmap, vin, vout, dPa, dPb, dMa, dMb,
                                       (j == 0) ? 1 : 0);
      float* t = vin; vin = vout; vout = t;
    }

    k_slice_d<<<NB, 256, 0, stream>>>(image, vin, out);
    return;
  }

  // ---- Hash fallback path ----
  struct Cfg { int tb; size_t M; };
  const Cfg cfgs[] = {
    {23, (size_t)NP5}, {23, 3200000}, {22, 2000000}, {21, 1500000}, {20, 1000000}
  };
  const int NCFG = sizeof(cfgs) / sizeof(cfgs[0]);

  int tbits = 20; size_t Mmax = 1000000;
  size_t off_hkeys = 0, off_hidx = 0, off_head2 = 0, off_cnt = 0, off_slots2 = 0,
         off_bary = 0, off_next = 0, off_lkeys = 0, off_lslot = 0, off_qp2 = 0,
         off_vA2 = 0, off_vB2 = 0;
  for (int i = 0; i < NCFG; i++){
    size_t T = (size_t)1 << cfgs[i].tb; size_t M = cfgs[i].M;
    size_t oo = 0;
    off_hkeys = oo; oo += T * 8;
    off_hidx  = oo; oo += T * 4;
    off_head2 = oo; oo += T * 4;
    off_cnt   = oo; oo += 256;
    off_slots2= oo; oo += (size_t)NP5 * 4;
    off_bary  = oo; oo += (size_t)NP5 * 4;
    off_next  = oo; oo += (size_t)NP5 * 4;
    off_lkeys = oo; oo += M * 8;
    off_lslot = oo; oo += M * 4;
    off_qp2   = oo; oo += (size_t)NPTS * 16;
    off_vA2   = oo; oo += M * 5 * 4;
    off_vB2   = oo; oo += M * 5 * 4;
    tbits = cfgs[i].tb; Mmax = M;
    if (oo <= ws_size) break;
  }
  size_t T = (size_t)1 << tbits;
  unsigned int tmask = (unsigned int)(T - 1);

  unsigned long long* hkeys = (unsigned long long*)(ws + off_hkeys);
  int*                hidx  = (int*)(ws + off_hidx);
  int*                head  = (int*)(ws + off_head2);
  int*                cnt   = (int*)(ws + off_cnt);
  int*                slots = (int*)(ws + off_slots2);
  float*              bary  = (float*)(ws + off_bary);
  int*                nexte = (int*)(ws + off_next);
  unsigned long long* lkeys = (unsigned long long*)(ws + off_lkeys);
  int*                lslot = (int*)(ws + off_lslot);
  float4*             qp    = (float4*)(ws + off_qp2);
  float*              valsA = (float*)(ws + off_vA2);
  float*              valsB = (float*)(ws + off_vB2);

  hipMemsetAsync(ws + off_hkeys, 0xFF, T * 8 + T * 4 + T * 4, stream);
  hipMemsetAsync(ws + off_cnt, 0, 256, stream);

  const int MB = (int)((Mmax + 255) / 256);

  k_qpack<<<NB, 256, 0, stream>>>(input_, qp);
  k_build_h<<<NB, 256, 0, stream>>>(image, hkeys, tmask, slots, bary, head, nexte,
                                    hidx, lkeys, lslot, cnt, (int)Mmax);
  k_gather_h<<<MB, 256, 0, stream>>>(lslot, head, nexte, bary, qp, valsA, cnt, (int)Mmax);

  const long long P3 = 1ll << 39, P2 = 1ll << 26, P1 = 1ll << 13, P0 = 1ll;
  const long long Dall = P3 + P2 + P1 + P0;
  const long long deltas[5] = { Dall - 5*P3, Dall - 5*P2, Dall - 5*P1, Dall - 5*P0, Dall };

  float* vin = valsA; float* vout = valsB;
  for (int j = 0; j < 5; j++){
    k_blur_h<<<MB, 256, 0, stream>>>(hkeys, hidx, lkeys, vin, vout, cnt, tmask, deltas[j], (int)Mmax);
    float* t = vin; vin = vout; vout = t;
  }

  k_slice_h<<<NB, 256, 0, stream>>>(slots, bary, hidx, vin, out, cnt, (int)Mmax);
}

// Round 9
// 280.973 us; speedup vs baseline: 1.7247x; 1.0053x over previous
//
#include <hip/hip_runtime.h>
#include <stdint.h>

#define NPTS (96*96*96)          // 884736
#define NP5  (NPTS*5)            // 4423680 entries (point,vertex)

// Dense lattice grid (interval arithmetic from fixed domain: z,y,x in [0,95],
// image in [0,1); incl. rank-adjust, r-offset, blur padding, +/-2 margin):
//   q0 in [-3,25], q1 in [-14,14], q2 in [-16,8], q3 in [-17,3]
#define GD1 33
#define GD2 29
#define GD3 25
#define GO0 5
#define GO1 16
#define GO2 18
#define GO3 19
#define GS3 5
#define GS2 (GD3*GS3)      // 125
#define GS1 (GD2*GS2)      // 3625
#define GS0 (GD1*GS1)      // 119625
#define GCELLS (31*GS0)    // 3708375
#define GCELLS1 (GCELLS+1) // + trash cell for (never-expected) OOB
#define GSSUM (GS0+GS1+GS2+GS3)  // 123380

#define LHS 2048           // block-local LDS hash slots (1280 entries -> load <=0.625)

struct BN { float w; int next; };   // bary weight + chain link (fallback path)
struct LatPt { int cell[5]; float w[5]; };

// Pack input_ channels into float4 per point (fallback path only)
__global__ void k_qpack(const float* __restrict__ input_, float4* __restrict__ qp)
{
  int n = blockIdx.x * blockDim.x + threadIdx.x;
  if (n >= NPTS) return;
  qp[n] = make_float4(input_[n], input_[NPTS + n], input_[2 * NPTS + n], input_[3 * NPTS + n]);
}

// Shared per-point lattice math macro producing rank[5], rem0i[4], b[]
#define LATTICE_MATH(n)                                                        \
  int x = n % 96, y = (n / 96) % 96, z = n / (96 * 96);                        \
  float cf[4];                                                                 \
  cf[0] = ((float)z / 5.0f) * 2.8867513459481287f;                             \
  cf[1] = ((float)y / 5.0f) * 1.6666666666666667f;                             \
  cf[2] = ((float)x / 5.0f) * 1.1785113019775793f;                             \
  cf[3] = (imgv / 0.25f) * 0.9128709291752769f;                                \
  float elev[5];                                                               \
  float sm = 0.f;                                                              \
  _Pragma("unroll")                                                            \
  for (int i = 4; i >= 1; --i){ float c = cf[i-1]; elev[i] = sm - (float)i * c; sm += c; } \
  elev[0] = sm;                                                                \
  float rem0[5]; float sumrd_f = 0.f;                                          \
  _Pragma("unroll")                                                            \
  for (int i = 0; i < 5; i++){ float rd = rintf(elev[i] / 5.0f); rem0[i] = rd * 5.0f; sumrd_f += rd; } \
  int sum_rd = (int)sumrd_f;                                                   \
  float diff[5];                                                               \
  _Pragma("unroll")                                                            \
  for (int i = 0; i < 5; i++) diff[i] = elev[i] - rem0[i];                     \
  int rank[5];                                                                 \
  _Pragma("unroll")                                                            \
  for (int i = 0; i < 5; i++){                                                 \
    int r = 0;                                                                 \
    _Pragma("unroll")                                                          \
    for (int j = 0; j < 5; j++){                                               \
      r += (diff[j] > diff[i] || (diff[j] == diff[i] && j < i)) ? 1 : 0;       \
    }                                                                          \
    rank[i] = r + sum_rd;                                                      \
  }                                                                            \
  _Pragma("unroll")                                                            \
  for (int i = 0; i < 5; i++){                                                 \
    if (rank[i] < 0)      { rank[i] += 5; rem0[i] += 5.0f; }                   \
    else if (rank[i] > 4) { rank[i] -= 5; rem0[i] -= 5.0f; }                   \
  }                                                                            \
  float b[6] = {0.f,0.f,0.f,0.f,0.f,0.f};                                      \
  _Pragma("unroll")                                                            \
  for (int i = 0; i < 5; i++){                                                 \
    float v = (elev[i] - rem0[i]) / 5.0f;                                      \
    b[4 - rank[i]] += v;                                                       \
    b[5 - rank[i]] -= v;                                                       \
  }                                                                            \
  b[0] += 1.0f + b[5];                                                         \
  int rem0i[4];                                                                \
  _Pragma("unroll")                                                            \
  for (int i = 0; i < 4; i++) rem0i[i] = (int)rem0[i];

// Dense-path per-point result: 5 cells + 5 weights (shared by build & slice —
// single implementation keeps the fp32 arithmetic bit-identical).
__device__ __forceinline__ LatPt lat_compute(int n, float imgv)
{
  LATTICE_MATH(n)
  LatPt p;
  #pragma unroll
  for (int r = 0; r < 5; r++){
    int q0 = (rem0i[0] / 5) - (rank[0] < 5 - r ? 0 : 1) + GO0;
    int q1 = (rem0i[1] / 5) - (rank[1] < 5 - r ? 0 : 1) + GO1;
    int q2 = (rem0i[2] / 5) - (rank[2] < 5 - r ? 0 : 1) + GO2;
    int q3 = (rem0i[3] / 5) - (rank[3] < 5 - r ? 0 : 1) + GO3;
    int cell = (((q0 * GD1 + q1) * GD2 + q2) * GD3 + q3) * 5 + r;
    if ((unsigned)cell >= (unsigned)GCELLS) cell = GCELLS;
    p.cell[r] = cell;
    p.w[r] = b[r];
  }
  return p;
}

// ====================== PATH A: LDS VALUE AGGREGATION ======================

// Phase 1: per-block LDS hash accumulates w*(q0..q3,1) per distinct cell via
// LDS float atomics; emission writes ONE pre-summed node per distinct cell
// (single global atomicExch splice). Nodes are SoA: nxt / wq03 / w4.
__global__ void k_build_agg(const float* __restrict__ image,
                            const float* __restrict__ input_,
                            int* __restrict__ head,
                            int* __restrict__ nxt,
                            float4* __restrict__ wq03,
                            float* __restrict__ w4a)
{
  __shared__ int   ls_cell[LHS];
  __shared__ float ls_wq[LHS * 5];
  __shared__ int   ls_cnt;

  int tid = threadIdx.x;
  #pragma unroll
  for (int i = 0; i < LHS / 256; i++){
    ls_cell[tid + 256 * i] = -1;
    #pragma unroll
    for (int c = 0; c < 5; c++) ls_wq[(tid + 256 * i) * 5 + c] = 0.f;
  }
  if (tid == 0) ls_cnt = 0;
  __syncthreads();

  int n = blockIdx.x * 256 + tid;
  float q0 = input_[n], q1 = input_[NPTS + n], q2 = input_[2 * NPTS + n], q3 = input_[3 * NPTS + n];
  LatPt P = lat_compute(n, image[n]);

  #pragma unroll
  for (int r = 0; r < 5; r++){
    int cell = P.cell[r];
    unsigned int h = ((unsigned int)cell * 2654435761u) & (LHS - 1);
    while (true){
      int prev = atomicCAS(&ls_cell[h], -1, cell);
      if (prev == -1 || prev == cell) break;
      h = (h + 1) & (LHS - 1);
    }
    float w = P.w[r];
    atomicAdd(&ls_wq[h * 5 + 0], w * q0);
    atomicAdd(&ls_wq[h * 5 + 1], w * q1);
    atomicAdd(&ls_wq[h * 5 + 2], w * q2);
    atomicAdd(&ls_wq[h * 5 + 3], w * q3);
    atomicAdd(&ls_wq[h * 5 + 4], w);
  }
  __syncthreads();

  int blockBase = blockIdx.x * 1280;
  for (int i = tid; i < LHS; i += 256){
    int cell = ls_cell[i];
    if (cell < 0) continue;
    int li = atomicAdd(&ls_cnt, 1);       // LDS counter: compact node index
    int node = blockBase + li;
    int old = atomicExch(&head[cell], node);
    nxt[node]  = old;
    wq03[node] = make_float4(ls_wq[i * 5 + 0], ls_wq[i * 5 + 1], ls_wq[i * 5 + 2], ls_wq[i * 5 + 3]);
    w4a[node]  = ls_wq[i * 5 + 4];
  }
}

// Phase 2: gather — walk short node chains (pre-summed per block), no value
// indirection. Emits occupancy bitmap via wave ballot.
__global__ void k_gather_agg(const int* __restrict__ head,
                             const int* __restrict__ nxt,
                             const float4* __restrict__ wq03,
                             const float* __restrict__ w4a,
                             float* __restrict__ vals,
                             unsigned int* __restrict__ bitmap)
{
  int c = blockIdx.x * blockDim.x + threadIdx.x;
  int e = -1;
  if (c < GCELLS1) e = head[c];
  bool occ = (e >= 0);
  unsigned long long mask = __ballot(occ);
  int lane = threadIdx.x & 63;
  if (lane == 0)       bitmap[c >> 5] = (unsigned int)(mask & 0xffffffffu);
  else if (lane == 32) bitmap[c >> 5] = (unsigned int)(mask >> 32);
  if (c >= GCELLS1) return;

  float s0 = 0.f, s1 = 0.f, s2 = 0.f, s3 = 0.f, s4 = 0.f;
  while (e >= 0){
    int en = nxt[e];              // dependent 4B load issues first
    float4 wq = wq03[e];
    float w4 = w4a[e];
    s0 += wq.x; s1 += wq.y; s2 += wq.z; s3 += wq.w; s4 += w4;
    e = en;
  }
  float* v = vals + (size_t)c * 5;
  v[0] = s0; v[1] = s1; v[2] = s2; v[3] = s3; v[4] = s4;
}

// ====================== PATH B (fallback): R8 scheme ======================

__global__ void k_build_lds(const float* __restrict__ image,
                            int* __restrict__ head,
                            BN* __restrict__ bnext)
{
  __shared__ int ls_cell[LHS];
  __shared__ int ls_head[LHS];

  int tid = threadIdx.x;
  #pragma unroll
  for (int i = 0; i < LHS / 256; i++){
    ls_cell[tid + 256 * i] = -1;
    ls_head[tid + 256 * i] = -1;
  }
  __syncthreads();

  int n = blockIdx.x * 256 + tid;
  LatPt P = lat_compute(n, image[n]);
  int blockBase = blockIdx.x * 1280;

  int lold[5]; unsigned int hs[5];
  #pragma unroll
  for (int r = 0; r < 5; r++){
    int cell = P.cell[r];
    unsigned int h = ((unsigned int)cell * 2654435761u) & (LHS - 1);
    while (true){
      int prev = atomicCAS(&ls_cell[h], -1, cell);
      if (prev == -1 || prev == cell) break;
      h = (h + 1) & (LHS - 1);
    }
    hs[r] = h;
    lold[r] = atomicExch(&ls_head[h], tid * 5 + r);
  }
  __syncthreads();

  #pragma unroll
  for (int r = 0; r < 5; r++){
    int e = blockBase + tid * 5 + r;
    int nxt2;
    if (lold[r] < 0){
      int lhead = ls_head[hs[r]];
      nxt2 = atomicExch(&head[P.cell[r]], blockBase + lhead);
    } else {
      nxt2 = blockBase + lold[r];
    }
    BN bn; bn.w = P.w[r]; bn.next = nxt2;
    bnext[e] = bn;
  }
}

__global__ void k_gather_d(const int* __restrict__ head,
                           const BN* __restrict__ bnext,
                           const float4* __restrict__ qp,
                           float* __restrict__ vals,
                           unsigned int* __restrict__ bitmap)
{
  int c = blockIdx.x * blockDim.x + threadIdx.x;
  int e = -1;
  if (c < GCELLS1) e = head[c];
  bool occ = (e >= 0);
  unsigned long long mask = __ballot(occ);
  int lane = threadIdx.x & 63;
  if (lane == 0)       bitmap[c >> 5] = (unsigned int)(mask & 0xffffffffu);
  else if (lane == 32) bitmap[c >> 5] = (unsigned int)(mask >> 32);
  if (c >= GCELLS1) return;

  float s0 = 0.f, s1 = 0.f, s2 = 0.f, s3 = 0.f, s4 = 0.f;
  while (e >= 0){
    BN bn = bnext[e];
    float4 q = qp[e / 5];
    s0 += bn.w * q.x; s1 += bn.w * q.y; s2 += bn.w * q.z; s3 += bn.w * q.w; s4 += bn.w;
    e = bn.next;
  }
  float* v = vals + (size_t)c * 5;
  v[0] = s0; v[1] = s1; v[2] = s2; v[3] = s3; v[4] = s4;
}

// ====================== SHARED: blur + slice ======================

__global__ void k_blur_d(const unsigned int* __restrict__ bitmap,
                         const float* __restrict__ vin,
                         float* __restrict__ vout,
                         int dPa, int dPb, int dMa, int dMb, int zfill)
{
  int c = blockIdx.x * blockDim.x + threadIdx.x;
  if (c >= GCELLS) return;
  unsigned int w = bitmap[c >> 5];
  if (!((w >> (c & 31)) & 1u)){
    if (zfill){
      float* vo = vout + (size_t)c * 5;
      vo[0] = 0.f; vo[1] = 0.f; vo[2] = 0.f; vo[3] = 0.f; vo[4] = 0.f;
    }
    return;
  }
  int r = c % 5;
  int p1 = c + (r == 4 ? dPb : dPa);
  int p2 = c + (r == 0 ? dMb : dMa);
  float* vo = vout + (size_t)c * 5;
  const float* va = vin + (size_t)c * 5;
  const float* n1 = vin + (size_t)p1 * 5;  // empty neighbors hold zeros
  const float* n2 = vin + (size_t)p2 * 5;
  #pragma unroll
  for (int ch = 0; ch < 5; ch++)
    vo[ch] = 0.5f * va[ch] + 0.25f * (n1[ch] + n2[ch]);
}

__global__ void k_slice_d(const float* __restrict__ image,
                          const float* __restrict__ vals,
                          float* __restrict__ out)
{
  int n = blockIdx.x * blockDim.x + threadIdx.x;
  if (n >= NPTS) return;
  LatPt P = lat_compute(n, image[n]);

  float s0 = 0.f, s1 = 0.f, s2 = 0.f, s3 = 0.f, s4 = 0.f;
  #pragma unroll
  for (int r = 0; r < 5; r++){
    float w = P.w[r];
    const float* v = vals + (size_t)P.cell[r] * 5;
    s0 += w * v[0]; s1 += w * v[1]; s2 += w * v[2]; s3 += w * v[3]; s4 += w * v[4];
  }
  float denom = s4 + 2.2204460492503131e-16f;
  out[n]            = s0 / denom;
  out[NPTS + n]     = s1 / denom;
  out[2 * NPTS + n] = s2 / denom;
  out[3 * NPTS + n] = s3 / denom;
}

// ============================ HOST ============================

extern "C" void kernel_launch(void* const* d_in, const int* in_sizes, int n_in,
                              void* d_out, int out_size, void* d_ws, size_t ws_size,
                              hipStream_t stream)
{
  const float* input_ = (const float*)d_in[0];
  const float* image  = (const float*)d_in[1];
  float* out = (float*)d_out;
  char* ws = (char*)d_ws;

  const int NB = (NPTS + 255) / 256;
  const int CB = (GCELLS1 + 255) / 256;
  const size_t BMWORDS = (size_t)CB * 8;
  const int Sj[5] = { GS0, GS1, GS2, GS3, 0 };

  // ---- Path A workspace: node SoA (pre-summed per block-cell) ----
  {
    size_t o = 0;
    size_t off_head = o; o += (size_t)GCELLS1 * 4;      o = (o + 255) & ~(size_t)255;
    size_t off_bm   = o; o += BMWORDS * 4;              o = (o + 255) & ~(size_t)255;
    size_t off_nxt  = o; o += (size_t)NP5 * 4;          o = (o + 255) & ~(size_t)255;
    size_t off_wq   = o; o += (size_t)NP5 * 16;         o = (o + 255) & ~(size_t)255;
    size_t off_w4   = o; o += (size_t)NP5 * 4;          o = (o + 255) & ~(size_t)255;
    size_t off_vA   = o; o += (size_t)GCELLS1 * 5 * 4;  o = (o + 255) & ~(size_t)255;
    size_t off_vB   = o; o += (size_t)GCELLS1 * 5 * 4;
    if (o <= ws_size){
      int*          head   = (int*)(ws + off_head);
      unsigned int* bitmap = (unsigned int*)(ws + off_bm);
      int*          nxt    = (int*)(ws + off_nxt);
      float4*       wq03   = (float4*)(ws + off_wq);
      float*        w4a    = (float*)(ws + off_w4);
      float*        valsA  = (float*)(ws + off_vA);
      float*        valsB  = (float*)(ws + off_vB);

      hipMemsetAsync(head, 0xFF, (size_t)GCELLS1 * 4, stream);

      k_build_agg<<<NB, 256, 0, stream>>>(image, input_, head, nxt, wq03, w4a);
      k_gather_agg<<<CB, 256, 0, stream>>>(head, nxt, wq03, w4a, valsA, bitmap);

      float* vin = valsA; float* vout = valsB;
      for (int j = 0; j < 5; j++){
        int dPa = 1 - Sj[j];
        int dPb = GSSUM - Sj[j] - 4;
        int dMa = Sj[j] - 1;
        int dMb = Sj[j] - GSSUM + 4;
        k_blur_d<<<CB, 256, 0, stream>>>(bitmap, vin, vout, dPa, dPb, dMa, dMb,
                                         (j == 0) ? 1 : 0);
        float* t = vin; vin = vout; vout = t;
      }

      k_slice_d<<<NB, 256, 0, stream>>>(image, vin, out);
      return;
    }
  }

  // ---- Path B fallback: R8 per-entry chains ----
  size_t o = 0;
  size_t off_head  = o; o += (size_t)GCELLS1 * 4;      o = (o + 255) & ~(size_t)255;
  size_t off_bm    = o; o += BMWORDS * 4;              o = (o + 255) & ~(size_t)255;
  size_t off_bnext = o; o += (size_t)NP5 * 8;          o = (o + 255) & ~(size_t)255;
  size_t off_qp    = o; o += (size_t)NPTS * 16;        o = (o + 255) & ~(size_t)255;
  size_t off_vA    = o; o += (size_t)GCELLS1 * 5 * 4;  o = (o + 255) & ~(size_t)255;
  size_t off_vB    = o; o += (size_t)GCELLS1 * 5 * 4;

  int*          head   = (int*)(ws + off_head);
  unsigned int* bitmap = (unsigned int*)(ws + off_bm);
  BN*           bnext  = (BN*)(ws + off_bnext);
  float4*       qp     = (float4*)(ws + off_qp);
  float*        valsA  = (float*)(ws + off_vA);
  float*        valsB  = (float*)(ws + off_vB);

  hipMemsetAsync(head, 0xFF, (size_t)GCELLS1 * 4, stream);

  k_qpack<<<NB, 256, 0, stream>>>(input_, qp);
  k_build_lds<<<NB, 256, 0, stream>>>(image, head, bnext);
  k_gather_d<<<CB, 256, 0, stream>>>(head, bnext, qp, valsA, bitmap);

  float* vin = valsA; float* vout = valsB;
  for (int j = 0; j < 5; j++){
    int dPa = 1 - Sj[j];
    int dPb = GSSUM - Sj[j] - 4;
    int dMa = Sj[j] - 1;
    int dMb = Sj[j] - GSSUM + 4;
    k_blur_d<<<CB, 256, 0, stream>>>(bitmap, vin, vout, dPa, dPb, dMa, dMb,
                                     (j == 0) ? 1 : 0);
    float* t = vin; vin = vout; vout = t;
  }

  k_slice_d<<<NB, 256, 0, stream>>>(image, vin, out);
}